// Round 6
// baseline (374.667 us; speedup 1.0000x reference)
//
#include <hip/hip_runtime.h>
#include <hip/hip_fp16.h>
#include <math.h>

// Problem constants (match reference)
constexpr int D     = 64;    // input feature dim
constexpr int H     = 14;    // hidden dim (2*LAT)
constexpr int HP    = 16;    // padded feature stride (64B rows)
constexpr int P     = 16;    // (LAT+1)*R
constexpr int LATc  = 7;
constexpr int OUTW  = 30;    // 7 + 7 + 14 + 2
constexpr float SP_INV_1 = 0.5413248546129181f; // log(expm1(1))

constexpr int RB_LOG = 7;    // 128 rows per bucket
constexpr int RB     = 128;
constexpr int MAXNB  = 800;  // >= ceil(100000/128) = 782
constexpr int CHUNK  = 8192; // edges per binscatter block

// ---------------- Dense: XW = X @ W1 (padded to 16), (N,64)@(64,14) -------
__global__ void dense_xw_kernel(const float* __restrict__ X,
                                const float* __restrict__ W1,
                                float* __restrict__ XW, int N) {
    __shared__ float w[D * H];
    for (int i = threadIdx.x; i < D * H; i += blockDim.x) w[i] = W1[i];
    __syncthreads();
    int n = blockIdx.x * blockDim.x + threadIdx.x;
    if (n >= N) return;
    float acc[H];
#pragma unroll
    for (int j = 0; j < H; ++j) acc[j] = 0.f;
    const float4* xr = reinterpret_cast<const float4*>(X + (size_t)n * D);
#pragma unroll
    for (int d4 = 0; d4 < D / 4; ++d4) {
        float4 x = xr[d4];
        float xs[4] = {x.x, x.y, x.z, x.w};
#pragma unroll
        for (int k = 0; k < 4; ++k) {
            int d = d4 * 4 + k;
#pragma unroll
            for (int j = 0; j < H; ++j) acc[j] = fmaf(xs[k], w[d * H + j], acc[j]);
        }
    }
    float* o = XW + (size_t)n * HP;
#pragma unroll
    for (int j = 0; j < H; ++j) o[j] = acc[j];
    o[14] = 0.f; o[15] = 0.f;
}

// ---------------- Coarse bucket histogram (LDS-aggregated) -----------------
__global__ void hist_kernel(const int* __restrict__ rows, int* __restrict__ ghist,
                            int E, int NB) {
    __shared__ int h[MAXNB];
    for (int i = threadIdx.x; i < NB; i += blockDim.x) h[i] = 0;
    __syncthreads();
    for (int i = blockIdx.x * blockDim.x + threadIdx.x; i < E; i += gridDim.x * blockDim.x)
        atomicAdd(&h[rows[i] >> RB_LOG], 1);
    __syncthreads();
    for (int i = threadIdx.x; i < NB; i += blockDim.x)
        if (h[i] > 0) atomicAdd(&ghist[i], h[i]);
}

// ---------------- Bucket scan: bstart = exscan(ghist); init gcursor --------
__global__ void scan_kernel(const int* __restrict__ ghist, int* __restrict__ bstart,
                            int* __restrict__ gcursor, int NB, int E) {
    __shared__ int s[1024];
    int tid = threadIdx.x;
    int v = (tid < NB) ? ghist[tid] : 0;
    s[tid] = v;
    __syncthreads();
    for (int off = 1; off < 1024; off <<= 1) {
        int t = (tid >= off) ? s[tid - off] : 0;
        __syncthreads();
        s[tid] += t;
        __syncthreads();
    }
    if (tid < NB) {
        int ex = s[tid] - v;
        bstart[tid] = ex;
        gcursor[tid] = ex;
    }
    if (tid == 0) bstart[NB] = E;
}

// ---------------- Block-local binned scatter -------------------------------
// Each block: LDS hist -> LDS scan -> global reserve -> LDS scatter -> flush.
// Entry: x = (col<<15)|fp16bits(val) (sign dropped, val in [0,1)), y = row.
__global__ __launch_bounds__(256) void binscatter_kernel(
        const int* __restrict__ rows, const int* __restrict__ cols,
        const float* __restrict__ vals, int* __restrict__ gcursor,
        uint2* __restrict__ ebin, int E, int NB) {
    __shared__ int cnt[MAXNB], startv[MAXNB], addrv[MAXNB];
    __shared__ int tmp[256];
    __shared__ int carry;
    __shared__ uint2 entries[CHUNK];

    int base = blockIdx.x * CHUNK;
    int lim = min(CHUNK, E - base);

    for (int i = threadIdx.x; i < NB; i += 256) cnt[i] = 0;
    if (threadIdx.x == 0) carry = 0;
    __syncthreads();

    // phase 1: local histogram
    for (int i = threadIdx.x; i < lim; i += 256)
        atomicAdd(&cnt[rows[base + i] >> RB_LOG], 1);
    __syncthreads();

    // phase 2: exclusive scan cnt -> startv (chunks of 256, Hillis-Steele)
    for (int c0 = 0; c0 < NB; c0 += 256) {
        int idx = c0 + threadIdx.x;
        int v = (idx < NB) ? cnt[idx] : 0;
        tmp[threadIdx.x] = v;
        __syncthreads();
        for (int off = 1; off < 256; off <<= 1) {
            int t = (threadIdx.x >= off) ? tmp[threadIdx.x - off] : 0;
            __syncthreads();
            tmp[threadIdx.x] += t;
            __syncthreads();
        }
        if (idx < NB) startv[idx] = carry + tmp[threadIdx.x] - v;
        __syncthreads();
        if (threadIdx.x == 0) carry += tmp[255];
        __syncthreads();
    }

    // phase 2.5: reserve contiguous global range per bucket
    for (int b = threadIdx.x; b < NB; b += 256) {
        int c = cnt[b];
        int g = (c > 0) ? atomicAdd(&gcursor[b], c) : 0;
        addrv[b] = g - startv[b];
    }
    __syncthreads();

    // phase 3: scatter into LDS, bucket-sorted (startv becomes running cursor)
    for (int i = threadIdx.x; i < lim; i += 256) {
        int e = base + i;
        int r = rows[e];
        unsigned vb = (unsigned)__half_as_ushort(__float2half_rn(vals[e])) & 0x7FFFu;
        unsigned x = ((unsigned)cols[e] << 15) | vb;
        int p = atomicAdd(&startv[r >> RB_LOG], 1);
        entries[p] = make_uint2(x, (unsigned)r);
    }
    __syncthreads();

    // phase 4: flush bucket-sorted runs to global (coalesced-ish)
    for (int i = threadIdx.x; i < lim; i += 256) {
        uint2 en = entries[i];
        int b = (int)(en.y >> RB_LOG);
        ebin[addrv[b] + i] = en;
    }
}

// ---------------- SpMM layer 1 + fused dense (relu(Y)@W2) ------------------
// One block per 128-row bucket; LDS fp32-atomic accumulation, stride-17 pad.
__global__ __launch_bounds__(256) void spmm1_fused_kernel(
        const float* __restrict__ F, const uint2* __restrict__ ebin,
        const int* __restrict__ bstart, const float* __restrict__ W2,
        float* __restrict__ HW, int N) {
    __shared__ float Y[RB * 17];
    __shared__ float w[H * H];
    for (int i = threadIdx.x; i < RB * 17; i += 256) Y[i] = 0.f;
    for (int i = threadIdx.x; i < H * H; i += 256) w[i] = W2[i];
    __syncthreads();

    int b = blockIdx.x;
    int beg = bstart[b], end = bstart[b + 1];
    int wv = threadIdx.x >> 6;
    int lane = threadIdx.x & 63;
    int g = lane >> 4, f = lane & 15;
    for (int i = beg + wv * 4 + g; i < end; i += 16) {
        uint2 en = ebin[i];
        int c = (int)(en.x >> 15);
        float v = __half2float(__ushort_as_half((unsigned short)(en.x & 0x7FFFu)));
        int rl = (int)(en.y & (RB - 1));
        atomicAdd(&Y[rl * 17 + f], v * F[((size_t)c << 4) + f]);
    }
    __syncthreads();

    int r0 = b << RB_LOG;
    int t = threadIdx.x;
    if (t < RB && r0 + t < N) {
        float h[H];
#pragma unroll
        for (int j = 0; j < H; ++j) h[j] = fmaxf(Y[t * 17 + j], 0.f);
        float* o = HW + ((size_t)(r0 + t) << 4);
#pragma unroll
        for (int j = 0; j < H; ++j) {
            float a = 0.f;
#pragma unroll
            for (int i2 = 0; i2 < H; ++i2) a = fmaf(h[i2], w[i2 * H + j], a);
            o[j] = a;
        }
        o[14] = 0.f; o[15] = 0.f;
    }
}

// ---------------- SpMM layer 2 + fused heads (tanh/softplus) ---------------
__global__ __launch_bounds__(256) void spmm2_fused_kernel(
        const float* __restrict__ F, const uint2* __restrict__ ebin,
        const int* __restrict__ bstart,
        const float* __restrict__ Wd1, const float* __restrict__ bd1,
        const float* __restrict__ Wd2, const float* __restrict__ bd2,
        float* __restrict__ out, int N) {
    __shared__ float Y[RB * 17];
    __shared__ float wd1[H * H], wd2[H * P], b1[H], b2[P];
    for (int i = threadIdx.x; i < RB * 17; i += 256) Y[i] = 0.f;
    for (int i = threadIdx.x; i < H * H; i += 256) wd1[i] = Wd1[i];
    for (int i = threadIdx.x; i < H * P; i += 256) wd2[i] = Wd2[i];
    if (threadIdx.x < H) b1[threadIdx.x] = bd1[threadIdx.x];
    if (threadIdx.x < P) b2[threadIdx.x] = bd2[threadIdx.x];
    __syncthreads();

    int b = blockIdx.x;
    int beg = bstart[b], end = bstart[b + 1];
    int wv = threadIdx.x >> 6;
    int lane = threadIdx.x & 63;
    int g = lane >> 4, f = lane & 15;
    for (int i = beg + wv * 4 + g; i < end; i += 16) {
        uint2 en = ebin[i];
        int c = (int)(en.x >> 15);
        float v = __half2float(__ushort_as_half((unsigned short)(en.x & 0x7FFFu)));
        int rl = (int)(en.y & (RB - 1));
        atomicAdd(&Y[rl * 17 + f], v * F[((size_t)c << 4) + f]);
    }
    __syncthreads();

    int r0 = b << RB_LOG;
    int t = threadIdx.x;
    if (t < RB && r0 + t < N) {
        float h[H];
#pragma unroll
        for (int j = 0; j < H; ++j) h[j] = fmaxf(Y[t * 17 + j], 0.f);

        float pd[H];
#pragma unroll
        for (int j = 0; j < H; ++j) {
            float a = b1[j];
#pragma unroll
            for (int i2 = 0; i2 < H; ++i2) a = fmaf(h[i2], wd1[i2 * H + j], a);
            pd[j] = tanhf(a);
        }
        float pp[P];
#pragma unroll
        for (int j = 0; j < P; ++j) {
            float a = b2[j];
#pragma unroll
            for (int i2 = 0; i2 < H; ++i2) a = fmaf(h[i2], wd2[i2 * P + j], a);
            pp[j] = tanhf(a);
        }
        float* o = out + (size_t)(r0 + t) * OUTW;
#pragma unroll
        for (int k = 0; k < LATc; ++k) o[k] = pd[k];
#pragma unroll
        for (int k = 0; k < LATc; ++k) {
            float x = pd[LATc + k] + SP_INV_1;
            o[LATc + k] = log1pf(expf(x)); // softplus
        }
#pragma unroll
        for (int k = 0; k < H; ++k) o[14 + k] = pp[k];
        o[28] = pp[14];
        o[29] = pp[15];
    }
}

extern "C" void kernel_launch(void* const* d_in, const int* in_sizes, int n_in,
                              void* d_out, int out_size, void* d_ws, size_t ws_size,
                              hipStream_t stream) {
    const float* X    = (const float*)d_in[0];
    const int*   rows = (const int*)d_in[1];
    const int*   cols = (const int*)d_in[2];
    const float* vals = (const float*)d_in[3];
    const float* W1   = (const float*)d_in[4];
    const float* W2   = (const float*)d_in[5];
    const float* Wd1  = (const float*)d_in[6];
    const float* bd1  = (const float*)d_in[7];
    const float* Wd2  = (const float*)d_in[8];
    const float* bd2  = (const float*)d_in[9];
    float* out = (float*)d_out;

    const int N  = in_sizes[0] / D;          // 100000
    const int E  = in_sizes[1];              // 1000000
    const int NB = (N + RB - 1) / RB;        // 782 buckets

    // workspace: XW[N*16] | HW[N*16] (floats) | ghist[MAXNB] | bstart[MAXNB+1]
    //            | gcursor[MAXNB] (ints) | ebin[E] (uint2, 8B-aligned)
    float* XW = (float*)d_ws;
    float* HW = XW + (size_t)N * HP;
    int* ghist   = (int*)(HW + (size_t)N * HP);
    int* bstart  = ghist + MAXNB;
    int* gcursor = bstart + (MAXNB + 1);
    size_t eoff = ((size_t)(gcursor + MAXNB) + 7) & ~(size_t)7;
    uint2* ebin = (uint2*)eoff;

    hipMemsetAsync(ghist, 0, MAXNB * sizeof(int), stream);

    int blkN = (N + 255) / 256;
    int blkS = (E + CHUNK - 1) / CHUNK;      // 123 binscatter blocks

    dense_xw_kernel<<<blkN, 256, 0, stream>>>(X, W1, XW, N);
    hist_kernel<<<256, 256, 0, stream>>>(rows, ghist, E, NB);
    scan_kernel<<<1, 1024, 0, stream>>>(ghist, bstart, gcursor, NB, E);
    binscatter_kernel<<<blkS, 256, 0, stream>>>(rows, cols, vals, gcursor, ebin, E, NB);
    spmm1_fused_kernel<<<NB, 256, 0, stream>>>(XW, ebin, bstart, W2, HW, N);
    spmm2_fused_kernel<<<NB, 256, 0, stream>>>(HW, ebin, bstart, Wd1, bd1, Wd2, bd2, out, N);
}

// Round 8
// 221.526 us; speedup vs baseline: 1.6913x; 1.6913x over previous
//
#include <hip/hip_runtime.h>
#include <hip/hip_fp16.h>
#include <math.h>

// Problem constants (match reference)
constexpr int D     = 64;    // input feature dim
constexpr int H     = 14;    // hidden dim (2*LAT)
constexpr int HP2   = 8;     // padded feature stride in half2 units (16 halfs = 32B)
constexpr int P     = 16;    // (LAT+1)*R
constexpr int LATc  = 7;
constexpr int OUTW  = 30;    // 7 + 7 + 14 + 2
constexpr float SP_INV_1 = 0.5413248546129181f; // log(expm1(1))

// Packed fp16 atomic add: ROCm headers lack the atomicAdd(__half2*) overload,
// but gfx950 has the instruction. Emit it directly.
__device__ __forceinline__ void pk_atomic_add_f16(__half2* addr, __half2 val) {
    unsigned int bits = *reinterpret_cast<unsigned int*>(&val);
    asm volatile("global_atomic_pk_add_f16 %0, %1, off"
                 :
                 : "v"(addr), "v"(bits)
                 : "memory");
}

// ---------------- Dense: XW = fp16(X @ W1), (N,64)@(64,14) -----------------
__global__ void dense_xw_kernel(const float* __restrict__ X,
                                const float* __restrict__ W1,
                                __half2* __restrict__ XW, int N) {
    __shared__ float w[D * H];
    for (int i = threadIdx.x; i < D * H; i += blockDim.x) w[i] = W1[i];
    __syncthreads();
    int n = blockIdx.x * blockDim.x + threadIdx.x;
    if (n >= N) return;
    float acc[H];
#pragma unroll
    for (int j = 0; j < H; ++j) acc[j] = 0.f;
    const float4* xr = reinterpret_cast<const float4*>(X + (size_t)n * D);
#pragma unroll
    for (int d4 = 0; d4 < D / 4; ++d4) {
        float4 x = xr[d4];
        float xs[4] = {x.x, x.y, x.z, x.w};
#pragma unroll
        for (int k = 0; k < 4; ++k) {
            int d = d4 * 4 + k;
#pragma unroll
            for (int j = 0; j < H; ++j) acc[j] = fmaf(xs[k], w[d * H + j], acc[j]);
        }
    }
    __half2 ov[HP2];
#pragma unroll
    for (int j = 0; j < 7; ++j) ov[j] = __floats2half2_rn(acc[2 * j], acc[2 * j + 1]);
    ov[7] = __floats2half2_rn(0.f, 0.f);
    float4* dst = reinterpret_cast<float4*>(XW + (size_t)n * HP2);
    dst[0] = *reinterpret_cast<float4*>(&ov[0]);
    dst[1] = *reinterpret_cast<float4*>(&ov[4]);
}

// ---------------- SpMM with packed-fp16 atomics ----------------------------
// 8 lanes per edge; lane f in [0,7) handles features {2f, 2f+1} as one half2.
__global__ void spmm_pk_kernel(const __half2* __restrict__ F,
                               const int* __restrict__ rows,
                               const int* __restrict__ cols,
                               const float* __restrict__ vals,
                               __half2* __restrict__ Y, int E) {
    int idx = blockIdx.x * blockDim.x + threadIdx.x;
    int e = idx >> 3;
    int f = idx & 7;
    if (e >= E || f >= 7) return;
    int r = rows[e];
    int c = cols[e];
    float v = vals[e];
    float2 xf = __half22float2(F[c * HP2 + f]);
    __half2 p = __floats2half2_rn(v * xf.x, v * xf.y);
    pk_atomic_add_f16(&Y[r * HP2 + f], p);
}

// ---------------- Dense: HW = fp16(relu(Y1) @ W2), (N,14)@(14,14) ----------
__global__ void dense_hw_kernel(const __half2* __restrict__ Y1,
                                const float* __restrict__ W2,
                                __half2* __restrict__ HW, int N) {
    __shared__ float w[H * H];
    for (int i = threadIdx.x; i < H * H; i += blockDim.x) w[i] = W2[i];
    __syncthreads();
    int n = blockIdx.x * blockDim.x + threadIdx.x;
    if (n >= N) return;
    const float4* yr4 = reinterpret_cast<const float4*>(Y1 + (size_t)n * HP2);
    float4 ya = yr4[0], yb = yr4[1];
    __half2 yh[HP2];
    *reinterpret_cast<float4*>(&yh[0]) = ya;
    *reinterpret_cast<float4*>(&yh[4]) = yb;
    float h[H];
#pragma unroll
    for (int k = 0; k < 7; ++k) {
        float2 t = __half22float2(yh[k]);
        h[2 * k]     = fmaxf(t.x, 0.f);
        h[2 * k + 1] = fmaxf(t.y, 0.f);
    }
    float o[H];
#pragma unroll
    for (int j = 0; j < H; ++j) {
        float a = 0.f;
#pragma unroll
        for (int i = 0; i < H; ++i) a = fmaf(h[i], w[i * H + j], a);
        o[j] = a;
    }
    __half2 ov[HP2];
#pragma unroll
    for (int j = 0; j < 7; ++j) ov[j] = __floats2half2_rn(o[2 * j], o[2 * j + 1]);
    ov[7] = __floats2half2_rn(0.f, 0.f);
    float4* dst = reinterpret_cast<float4*>(HW + (size_t)n * HP2);
    dst[0] = *reinterpret_cast<float4*>(&ov[0]);
    dst[1] = *reinterpret_cast<float4*>(&ov[4]);
}

// ---------------- Fused tail: h2=relu(Y2) -> tanh heads -> output ----------
__global__ void final_kernel(const __half2* __restrict__ Y2,
                             const float* __restrict__ Wd1,
                             const float* __restrict__ bd1,
                             const float* __restrict__ Wd2,
                             const float* __restrict__ bd2,
                             float* __restrict__ out, int N) {
    __shared__ float wd1[H * H], wd2[H * P], b1[H], b2[P];
    for (int i = threadIdx.x; i < H * H; i += blockDim.x) wd1[i] = Wd1[i];
    for (int i = threadIdx.x; i < H * P; i += blockDim.x) wd2[i] = Wd2[i];
    if (threadIdx.x < H) b1[threadIdx.x] = bd1[threadIdx.x];
    if (threadIdx.x < P) b2[threadIdx.x] = bd2[threadIdx.x];
    __syncthreads();
    int n = blockIdx.x * blockDim.x + threadIdx.x;
    if (n >= N) return;

    const float4* yr4 = reinterpret_cast<const float4*>(Y2 + (size_t)n * HP2);
    float4 ya = yr4[0], yb = yr4[1];
    __half2 yh[HP2];
    *reinterpret_cast<float4*>(&yh[0]) = ya;
    *reinterpret_cast<float4*>(&yh[4]) = yb;
    float h[H];
#pragma unroll
    for (int k = 0; k < 7; ++k) {
        float2 t = __half22float2(yh[k]);
        h[2 * k]     = fmaxf(t.x, 0.f);
        h[2 * k + 1] = fmaxf(t.y, 0.f);
    }

    float pd[H];
#pragma unroll
    for (int j = 0; j < H; ++j) {
        float a = b1[j];
#pragma unroll
        for (int i = 0; i < H; ++i) a = fmaf(h[i], wd1[i * H + j], a);
        pd[j] = tanhf(a);
    }
    float pp[P];
#pragma unroll
    for (int j = 0; j < P; ++j) {
        float a = b2[j];
#pragma unroll
        for (int i = 0; i < H; ++i) a = fmaf(h[i], wd2[i * P + j], a);
        pp[j] = tanhf(a);
    }

    float* o = out + (size_t)n * OUTW;
#pragma unroll
    for (int k = 0; k < LATc; ++k) o[k] = pd[k];
#pragma unroll
    for (int k = 0; k < LATc; ++k) {
        float x = pd[LATc + k] + SP_INV_1;
        o[LATc + k] = log1pf(expf(x)); // softplus
    }
#pragma unroll
    for (int k = 0; k < H; ++k) o[14 + k] = pp[k];
    o[28] = pp[14];
    o[29] = pp[15];
}

extern "C" void kernel_launch(void* const* d_in, const int* in_sizes, int n_in,
                              void* d_out, int out_size, void* d_ws, size_t ws_size,
                              hipStream_t stream) {
    const float* X    = (const float*)d_in[0];
    const int*   rows = (const int*)d_in[1];
    const int*   cols = (const int*)d_in[2];
    const float* vals = (const float*)d_in[3];
    const float* W1   = (const float*)d_in[4];
    const float* W2   = (const float*)d_in[5];
    const float* Wd1  = (const float*)d_in[6];
    const float* bd1  = (const float*)d_in[7];
    const float* Wd2  = (const float*)d_in[8];
    const float* bd2  = (const float*)d_in[9];
    float* out = (float*)d_out;

    const int N = in_sizes[0] / D;   // 100000
    const int E = in_sizes[1];       // 1000000

    // workspace (half2, all 32B-strided): XW[N*8] | HW[N*8] | Y1[N*8] | Y2[N*8]
    __half2* XW = (__half2*)d_ws;
    __half2* HW = XW + (size_t)N * HP2;
    __half2* Y1 = HW + (size_t)N * HP2;
    __half2* Y2 = Y1 + (size_t)N * HP2;

    // zero both accumulators in one memset (adjacent); fp16 zero = 0x0000
    (void)hipMemsetAsync(Y1, 0, (size_t)N * HP2 * 2 * sizeof(__half2), stream);

    int blkN = (N + 255) / 256;
    long long spmmThreads = (long long)E * 8;
    unsigned blkS = (unsigned)((spmmThreads + 255) / 256);

    dense_xw_kernel<<<blkN, 256, 0, stream>>>(X, W1, XW, N);
    spmm_pk_kernel<<<blkS, 256, 0, stream>>>(XW, rows, cols, vals, Y1, E);
    dense_hw_kernel<<<blkN, 256, 0, stream>>>(Y1, W2, HW, N);
    spmm_pk_kernel<<<blkS, 256, 0, stream>>>(HW, rows, cols, vals, Y2, E);
    final_kernel<<<blkN, 256, 0, stream>>>(Y2, Wd1, bd1, Wd2, bd2, out, N);
}